// Round 2
// baseline (259.796 us; speedup 1.0000x reference)
//
#include <hip/hip_runtime.h>
#include <math.h>

#define TOK 16384
#define DD  2048
#define EE  64
#define MT  32           // tokens per block (2 tiles of 16 per wave)
#define KCW 32           // K-chunks (of 32) per wave; 2 waves split K=2048

typedef _Float16 half8  __attribute__((ext_vector_type(8)));
typedef float    floatx4 __attribute__((ext_vector_type(4)));

// ---- W pre-split: f32 -> (hi,lo) f16, chunk-major frag layout ----
// half8 frag index ((kc*8 + ct)*2 + s)*64 + lane.
// ct 0..3 = gate col-tiles (cols (ct&3)*16+cl), ct 4..7 = noise col-tiles.
__global__ void build_wf(const float* __restrict__ Wg, const float* __restrict__ Wn,
                         _Float16* __restrict__ wf) {
  int tid  = blockIdx.x * 256 + threadIdx.x;   // 32768 threads
  int lane = tid & 63;
  int kc   = (tid >> 6) & 63;
  int ct   = tid >> 12;                        // 0..7
  int col  = (ct & 3) * 16 + (lane & 15);
  int k    = kc * 32 + (lane >> 4) * 8;
  const float* W = (ct < 4) ? Wg : Wn;
  const float* src = W + (size_t)col * DD + k;
  float4 a = *reinterpret_cast<const float4*>(src);
  float4 b = *reinterpret_cast<const float4*>(src + 4);
  float v[8] = {a.x, a.y, a.z, a.w, b.x, b.y, b.z, b.w};
  half8 hi, lo;
#pragma unroll
  for (int j = 0; j < 8; ++j) {
    _Float16 h = (_Float16)v[j];
    hi[j] = h;
    lo[j] = (_Float16)(v[j] - (float)h);
  }
  size_t base = (((size_t)(kc * 8 + ct) * 2 + 0) * 64 + lane) * 8;
  *reinterpret_cast<half8*>(wf + base)       = hi;
  *reinterpret_cast<half8*>(wf + base + 512) = lo;   // s=1 frag
}

// One K-loop body. CUR/NXT are compile-time buffer indices (rule #20: no
// runtime-indexed register arrays). Order of MFMAs (hihi, hilo, lohi) and
// chunk order match the previous passing kernel bit-for-bit.
#define KBODY(kc, CUR, NXT)                                                        \
  {                                                                                \
    half8 Ah[2], Al[2];                                                            \
    _Pragma("unroll")                                                              \
    for (int mt = 0; mt < 2; ++mt) {                                               \
      float v[8] = {Aa[CUR][mt].x, Aa[CUR][mt].y, Aa[CUR][mt].z, Aa[CUR][mt].w,    \
                    Ab[CUR][mt].x, Ab[CUR][mt].y, Ab[CUR][mt].z, Ab[CUR][mt].w};   \
      _Pragma("unroll")                                                            \
      for (int j = 0; j < 8; ++j) {                                                \
        _Float16 h = (_Float16)v[j];                                               \
        Ah[mt][j] = h;                                                             \
        Al[mt][j] = (_Float16)(v[j] - (float)h);                                   \
      }                                                                            \
    }                                                                              \
    if ((kc) + 2 < KCW) {                                                          \
      _Pragma("unroll")                                                            \
      for (int mt = 0; mt < 2; ++mt) {                                             \
        Aa[CUR][mt] = *reinterpret_cast<const float4*>(xp[mt] + ((kc) + 2) * 32);  \
        Ab[CUR][mt] = *reinterpret_cast<const float4*>(xp[mt] + ((kc) + 2) * 32 + 4); \
      }                                                                            \
    }                                                                              \
    if ((kc) + 1 < KCW) {                                                          \
      _Pragma("unroll")                                                            \
      for (int f = 0; f < 16; ++f) Bf[NXT][f] = wp[((kc) + 1) * 1024 + f * 64];    \
    }                                                                              \
    _Pragma("unroll")                                                              \
    for (int mt = 0; mt < 2; ++mt)                                                 \
      _Pragma("unroll")                                                            \
      for (int ct = 0; ct < 8; ++ct)                                               \
        acc[mt][ct] = __builtin_amdgcn_mfma_f32_16x16x32_f16(                      \
            Ah[mt], Bf[CUR][ct * 2 + 0], acc[mt][ct], 0, 0, 0);                    \
    _Pragma("unroll")                                                              \
    for (int mt = 0; mt < 2; ++mt)                                                 \
      _Pragma("unroll")                                                            \
      for (int ct = 0; ct < 8; ++ct)                                               \
        acc[mt][ct] = __builtin_amdgcn_mfma_f32_16x16x32_f16(                      \
            Ah[mt], Bf[CUR][ct * 2 + 1], acc[mt][ct], 0, 0, 0);                    \
    _Pragma("unroll")                                                              \
    for (int mt = 0; mt < 2; ++mt)                                                 \
      _Pragma("unroll")                                                            \
      for (int ct = 0; ct < 8; ++ct)                                               \
        acc[mt][ct] = __builtin_amdgcn_mfma_f32_16x16x32_f16(                      \
            Al[mt], Bf[CUR][ct * 2 + 0], acc[mt][ct], 0, 0, 0);                    \
  }

// Barrier-free main loop: x loaded straight into A-frag registers (no LDS),
// B-frags streamed from L2-resident wf. 2 waves/block split K (merge once).
__global__ __launch_bounds__(128, 1)
void gating_kernel(const float* __restrict__ x, const float* __restrict__ rn,
                   const _Float16* __restrict__ wf, const float* __restrict__ bg,
                   float* __restrict__ out,
                   float* __restrict__ cnt_g, float* __restrict__ psum_g) {
  __shared__ float Pacc[64 * 64];   // 16384 B: wave-1 partial acc
  __shared__ float Vb[MT * 65];     // noisy logits
  __shared__ float Eb[MT * 65];     // exp(noisy)
  __shared__ float isum[MT];
  __shared__ int   ti[MT * 2];
  __shared__ float tp[MT * 2];

  const int t  = threadIdx.x;
  const int w  = t >> 6;        // K-half: 0 -> [0,1024), 1 -> [1024,2048)
  const int l  = t & 63;
  const int q  = l >> 4;
  const int cl = l & 15;
  const int t0 = blockIdx.x * MT;

  // A-frag native global addresses: lane l covers token row cl, k = q*8..q*8+7
  const float* xp[2];
  xp[0] = x + (size_t)(t0 + cl) * DD + w * (KCW * 32) + q * 8;
  xp[1] = xp[0] + (size_t)16 * DD;

  // B-frag base for this wave's K-half (half8 units)
  const half8* wp = reinterpret_cast<const half8*>(wf) + (size_t)(w * KCW) * 16 * 64 + l;

  floatx4 acc[2][8];            // [token-tile][col-tile: 0..3 gate, 4..7 noise]
#pragma unroll
  for (int mt = 0; mt < 2; ++mt)
#pragma unroll
    for (int ct = 0; ct < 8; ++ct) acc[mt][ct] = (floatx4)0.f;

  float4 Aa[2][2], Ab[2][2];    // [buf][mt] : A f32, double-buffered 2 chunks deep
  half8  Bf[2][16];             // [buf][ct*2+s] : B frags, 1 chunk deep

  // preamble: A chunks 0,1 ; B chunk 0
#pragma unroll
  for (int mt = 0; mt < 2; ++mt) {
    Aa[0][mt] = *reinterpret_cast<const float4*>(xp[mt]);
    Ab[0][mt] = *reinterpret_cast<const float4*>(xp[mt] + 4);
    Aa[1][mt] = *reinterpret_cast<const float4*>(xp[mt] + 32);
    Ab[1][mt] = *reinterpret_cast<const float4*>(xp[mt] + 36);
  }
#pragma unroll
  for (int f = 0; f < 16; ++f) Bf[0][f] = wp[f * 64];

  for (int kc2 = 0; kc2 < KCW; kc2 += 2) {
    KBODY(kc2, 0, 1)
    KBODY(kc2 + 1, 1, 0)
  }

  // ---- split-K merge: wave 1 -> LDS, wave 0 adds ----
  if (w == 1) {
#pragma unroll
    for (int mt = 0; mt < 2; ++mt)
#pragma unroll
      for (int ct = 0; ct < 8; ++ct)
#pragma unroll
        for (int r = 0; r < 4; ++r)
          Pacc[((mt * 8 + ct) * 4 + r) * 64 + l] = acc[mt][ct][r];
  }
  __syncthreads();

  if (w == 0) {
#pragma unroll
    for (int mt = 0; mt < 2; ++mt)
#pragma unroll
      for (int ct = 0; ct < 8; ++ct)
#pragma unroll
        for (int r = 0; r < 4; ++r)
          acc[mt][ct][r] += Pacc[((mt * 8 + ct) * 4 + r) * 64 + l];

    float bgv[4];
#pragma unroll
    for (int ct = 0; ct < 4; ++ct) bgv[ct] = bg[ct * 16 + cl];

    // noisy logit + exp, in-register (gate ct / noise ct+4 live in same lane)
#pragma unroll
    for (int mt = 0; mt < 2; ++mt)
#pragma unroll
      for (int ct = 0; ct < 4; ++ct)
#pragma unroll
        for (int r = 0; r < 4; ++r) {
          const int tk = mt * 16 + q * 4 + r;   // C/D layout: row = q*4+r
          const int c  = ct * 16 + cl;
          float gt = acc[mt][ct][r] + bgv[ct];
          float h  = acc[mt][ct + 4][r];
          float sp = (h > 20.f) ? h : log1pf(expf(h));
          float v  = gt + rn[(size_t)(t0 + tk) * EE + c] * (sp + 0.01f);
          Vb[tk * 65 + c] = v;
          Eb[tk * 65 + c] = expf(v);
        }
  }
  __syncthreads();

  // ---- per-token top-2 + softmax denom (32 threads) ----
  if (t < MT) {
    float v1 = -1e30f, v2 = -1e30f;
    int   i1 = 0, i2 = 0;
    float s = 0.f;
    for (int e = 0; e < EE; ++e) {
      float v = Vb[t * 65 + e];
      s += Eb[t * 65 + e];
      if (v > v1)      { v2 = v1; i2 = i1; v1 = v; i1 = e; }
      else if (v > v2) { v2 = v;  i2 = e; }
    }
    isum[t] = 1.f / s;
    ti[t * 2 + 0] = i1; ti[t * 2 + 1] = i2;
    float e2 = expf(v2 - v1);
    float dn = 1.f + e2;
    tp[t * 2 + 0] = 1.f / dn;
    tp[t * 2 + 1] = e2 / dn;
  }
  __syncthreads();

  // ---- sparse out: patched zero-fill, 128 threads x 4 float4 ----
#pragma unroll
  for (int i = 0; i < 4; ++i) {
    const int idx = t + i * 128;          // 0..511
    const int m   = idx >> 4;             // token 0..31
    const int c0  = (idx & 15) * 4;
    const int i1 = ti[m * 2 + 0], i2 = ti[m * 2 + 1];
    const float p1 = tp[m * 2 + 0], p2 = tp[m * 2 + 1];
    float o[4];
#pragma unroll
    for (int j = 0; j < 4; ++j) {
      const int col = c0 + j;
      o[j] = (col == i1) ? p1 : ((col == i2) ? p2 : 0.f);
    }
    *reinterpret_cast<float4*>(out + (size_t)(t0 + m) * EE + c0) =
        make_float4(o[0], o[1], o[2], o[3]);
  }

  // ---- aux partials: per-expert psum & count ----
  if (t < EE) {
    float s = 0.f;
    int   cn = 0;
#pragma unroll
    for (int m = 0; m < MT; ++m) {
      s  += Eb[m * 65 + t] * isum[m];
      cn += (ti[m * 2 + 0] == t) + (ti[m * 2 + 1] == t);
    }
    atomicAdd(&psum_g[t], s);
    atomicAdd(&cnt_g[t], (float)cn);
  }
}

__global__ void aux_kernel(const float* __restrict__ cnt_g,
                           const float* __restrict__ psum_g,
                           float* __restrict__ out) {
  int e = threadIdx.x;  // 64 lanes, one wave
  float v = cnt_g[e] * psum_g[e];
#pragma unroll
  for (int o = 32; o > 0; o >>= 1) v += __shfl_down(v, o);
  if (e == 0)
    out[(size_t)TOK * EE] = v * ((float)EE / ((float)TOK * (float)TOK));
}

extern "C" void kernel_launch(void* const* d_in, const int* in_sizes, int n_in,
                              void* d_out, int out_size, void* d_ws, size_t ws_size,
                              hipStream_t stream) {
  const float* x  = (const float*)d_in[0];
  const float* rn = (const float*)d_in[1];
  const float* Wg = (const float*)d_in[2];
  const float* bg = (const float*)d_in[3];
  const float* Wn = (const float*)d_in[4];
  float* out    = (float*)d_out;
  float* cnt_g  = (float*)d_ws;
  float* psum_g = cnt_g + EE;
  _Float16* wf  = (_Float16*)((float*)d_ws + 128);   // 1 MiB of pre-split W frags

  hipMemsetAsync(d_ws, 0, 2 * EE * sizeof(float), stream);
  build_wf<<<128, 256, 0, stream>>>(Wg, Wn, wf);
  gating_kernel<<<TOK / MT, 128, 0, stream>>>(x, rn, wf, bg, out, cnt_g, psum_g);
  aux_kernel<<<1, 64, 0, stream>>>(cnt_g, psum_g, out);
}